// Round 1
// baseline (38.555 us; speedup 1.0000x reference)
//
#include <hip/hip_runtime.h>
#include <math.h>

#define VOCAB 100000
#define EMB 128
#define BATCH 16384
#define NPOS 4
#define NNEG 20
#define EPSV 1e-3f

#define NBLOCKS 2048
#define NTHREADS 256
#define WAVES_PER_BLOCK (NTHREADS / 64)                    // 4
#define ELEMS_PER_WAVE (BATCH / (NBLOCKS * WAVES_PER_BLOCK)) // 2

// Main kernel: each wave processes ELEMS_PER_WAVE batch elements.
// Lanes split into 4 groups of 16; each group computes one sample dot per
// iteration (6 iterations cover 4 pos + 20 neg samples).
__global__ __launch_bounds__(NTHREADS) void w2v_main(
    const int* __restrict__ x,
    const int* __restrict__ pos,
    const int* __restrict__ neg,
    const float* __restrict__ emb,
    const float* __restrict__ outw,
    float* __restrict__ partials)
{
    const int tid  = threadIdx.x;
    const int lane = tid & 63;
    const int wid  = tid >> 6;
    const int g    = lane >> 4;   // group 0..3
    const int i    = lane & 15;   // lane within group

    const int wv = blockIdx.x * WAVES_PER_BLOCK + wid;

    float pos_acc = 0.0f;
    float neg_acc = 0.0f;

    for (int e = 0; e < ELEMS_PER_WAVE; ++e) {
        const int b  = wv * ELEMS_PER_WAVE + e;
        const int xb = x[b];

        // 512B emb row: lane i of every group holds elems [i*8, i*8+8)
        const float4* embr = (const float4*)(emb + (long)xb * EMB);
        const float4 e0 = embr[i * 2];
        const float4 e1 = embr[i * 2 + 1];

        float z0, z1, z2, z3, z4, z5;
#pragma unroll
        for (int iter = 0; iter < 6; ++iter) {
            int sidx;
            if (iter == 0) sidx = pos[b * NPOS + g];
            else           sidx = neg[b * NNEG + (iter - 1) * 4 + g];

            const float4* wr = (const float4*)(outw + (long)sidx * EMB);
            const float4 w0 = wr[i * 2];
            const float4 w1 = wr[i * 2 + 1];

            float p = e0.x * w0.x + e0.y * w0.y + e0.z * w0.z + e0.w * w0.w
                    + e1.x * w1.x + e1.y * w1.y + e1.z * w1.z + e1.w * w1.w;

            // 16-lane butterfly reduce (stays within the group: masks < 16)
            p += __shfl_xor(p, 1);
            p += __shfl_xor(p, 2);
            p += __shfl_xor(p, 4);
            p += __shfl_xor(p, 8);

            if      (iter == 0) z0 = p;
            else if (iter == 1) z1 = p;
            else if (iter == 2) z2 = p;
            else if (iter == 3) z3 = p;
            else if (iter == 4) z4 = p;
            else                z5 = p;
        }

        // One transcendental pass covers all 24 samples of this batch elem:
        // lane i (i<6) of group g finalizes sample (iter=i, group=g).
        if (i < 6) {
            float z = z0;
            z = (i == 1) ? z1 : z;
            z = (i == 2) ? z2 : z;
            z = (i == 3) ? z3 : z;
            z = (i == 4) ? z4 : z;
            z = (i == 5) ? z5 : z;
            const float t = __expf(-z);
            const float s = 1.0f / (1.0f + t);           // sigmoid(z)
            const float v = (i == 0) ? s : (1.0f - s + EPSV);
            const float term = __logf(v);
            if (i == 0) pos_acc += term;
            else        neg_acc += term;
        }
    }

    // wave-wide butterfly reduce
#pragma unroll
    for (int m = 1; m < 64; m <<= 1) {
        pos_acc += __shfl_xor(pos_acc, m);
        neg_acc += __shfl_xor(neg_acc, m);
    }

    __shared__ float sp[WAVES_PER_BLOCK];
    __shared__ float sn[WAVES_PER_BLOCK];
    if (lane == 0) { sp[wid] = pos_acc; sn[wid] = neg_acc; }
    __syncthreads();
    if (tid == 0) {
        float tp = 0.0f, tn = 0.0f;
#pragma unroll
        for (int w = 0; w < WAVES_PER_BLOCK; ++w) { tp += sp[w]; tn += sn[w]; }
        partials[blockIdx.x * 2]     = tp;
        partials[blockIdx.x * 2 + 1] = tn;
    }
}

// Finalize: single block reduces the 2048 block partials, writes scalar loss.
__global__ __launch_bounds__(256) void w2v_final(
    const float* __restrict__ partials, float* __restrict__ out)
{
    const int tid  = threadIdx.x;
    const int lane = tid & 63;
    const int wid  = tid >> 6;

    float tp = 0.0f, tn = 0.0f;
    for (int k = tid; k < NBLOCKS; k += 256) {
        tp += partials[k * 2];
        tn += partials[k * 2 + 1];
    }
#pragma unroll
    for (int m = 1; m < 64; m <<= 1) {
        tp += __shfl_xor(tp, m);
        tn += __shfl_xor(tn, m);
    }
    __shared__ float sp[4];
    __shared__ float sn[4];
    if (lane == 0) { sp[wid] = tp; sn[wid] = tn; }
    __syncthreads();
    if (tid == 0) {
        float fp = sp[0] + sp[1] + sp[2] + sp[3];
        float fn = sn[0] + sn[1] + sn[2] + sn[3];
        // loss = -mean(log(sigmoid(pos))) - mean(log(1 - sigmoid(neg) + eps))
        out[0] = -fp / (float)(BATCH * NPOS) - fn / (float)(BATCH * NNEG);
    }
}

extern "C" void kernel_launch(void* const* d_in, const int* in_sizes, int n_in,
                              void* d_out, int out_size, void* d_ws, size_t ws_size,
                              hipStream_t stream) {
    const int*   x    = (const int*)d_in[0];
    const int*   pos  = (const int*)d_in[1];
    const int*   neg  = (const int*)d_in[2];
    const float* emb  = (const float*)d_in[3];
    const float* outw = (const float*)d_in[4];
    float* out = (float*)d_out;
    float* partials = (float*)d_ws;   // NBLOCKS*2 floats, fully rewritten each launch

    w2v_main<<<NBLOCKS, NTHREADS, 0, stream>>>(x, pos, neg, emb, outw, partials);
    w2v_final<<<1, 256, 0, stream>>>(partials, out);
}